// Round 15
// baseline (99.748 us; speedup 1.0000x reference)
//
#include <hip/hip_runtime.h>

typedef __attribute__((ext_vector_type(4))) int i32x4;
typedef __attribute__((ext_vector_type(16))) int i32x16;

#define N 4096

// One block per row (8192 rows: Z then Y). fp32 row norm + absmax + i8 quant.
__global__ __launch_bounds__(256) void prep_kernel(
    const float* __restrict__ Z, const float* __restrict__ Y,
    char* __restrict__ Zq, char* __restrict__ Yq,
    float* __restrict__ norms, float* __restrict__ scales) {
  const int r = blockIdx.x;
  const bool isZ = (r < N);
  const int rr = isZ ? r : r - N;
  const float* __restrict__ src = (isZ ? Z : Y) + (size_t)rr * N;
  char* __restrict__ dst = (isZ ? Zq : Yq) + (size_t)rr * N;
  const int t = threadIdx.x;

  float4 v[4];
  float s = 0.f, amax = 0.f;
#pragma unroll
  for (int j = 0; j < 4; ++j) {
    v[j] = ((const float4*)src)[t * 4 + j];
    s += v[j].x * v[j].x + v[j].y * v[j].y + v[j].z * v[j].z + v[j].w * v[j].w;
    amax = fmaxf(amax, fmaxf(fmaxf(fabsf(v[j].x), fabsf(v[j].y)),
                             fmaxf(fabsf(v[j].z), fabsf(v[j].w))));
  }
#pragma unroll
  for (int off = 32; off > 0; off >>= 1) {
    s += __shfl_down(s, off, 64);
    amax = fmaxf(amax, __shfl_down(amax, off, 64));
  }
  __shared__ float reds[4], redm[4];
  const int lane = t & 63, w = t >> 6;
  if (lane == 0) { reds[w] = s; redm[w] = amax; }
  __syncthreads();
  const float bmax = fmaxf(fmaxf(redm[0], redm[1]), fmaxf(redm[2], redm[3]));
  if (t == 0) {
    norms[r] = sqrtf(reds[0] + reds[1] + reds[2] + reds[3]);
    scales[r] = bmax * (1.0f / 127.0f);
  }
  const float inv = (bmax > 0.f) ? (127.0f / bmax) : 0.f;
  int q[16];
#pragma unroll
  for (int j = 0; j < 4; ++j) {
    q[4 * j + 0] = __float2int_rn(v[j].x * inv);
    q[4 * j + 1] = __float2int_rn(v[j].y * inv);
    q[4 * j + 2] = __float2int_rn(v[j].z * inv);
    q[4 * j + 3] = __float2int_rn(v[j].w * inv);
  }
  int4 o;
  o.x = (q[0] & 255) | ((q[1] & 255) << 8) | ((q[2] & 255) << 16) | (q[3] << 24);
  o.y = (q[4] & 255) | ((q[5] & 255) << 8) | ((q[6] & 255) << 16) | (q[7] << 24);
  o.z = (q[8] & 255) | ((q[9] & 255) << 8) | ((q[10] & 255) << 16) | (q[11] << 24);
  o.w = (q[12] & 255) | ((q[13] & 255) << 8) | ((q[14] & 255) << 16) | (q[15] << 24);
  ((int4*)dst)[t] = o;
}

// ---- 256x256 tile, K-tile = 128 i8, r14 8-phase skeleton verbatim -------
// MFMA: mfma_i32_32x32x32_i8 (4404 TOPS vs 3944; half the instructions).
// Swizzle (both sides): 16B slot ^= (row&7) ^ ((row>>3)&3) -- within each
// 8-lane group of a 32-row fragment all 8 slots distinct (fixes r8's
// 32-row-pattern conflict). Regions/buf: A0@0 A1@16K B0@32K B1@48K; +64K.
__global__ __launch_bounds__(512, 2) void gemm_kernel(
    const char* __restrict__ A,       // Zq [N][N] i8
    const char* __restrict__ B,       // Yq [N][N] i8
    const float* __restrict__ norms,  // [2N]: nx then ny
    const float* __restrict__ scales, // [2N]: sx then sy
    float* __restrict__ out) {
  __shared__ __align__(16) char smem[131072];

  const int bid = blockIdx.x;                 // 256 blocks; bijective
  const int swz = (bid & 7) * 32 + (bid >> 3);
  const int tile_row = swz >> 4;
  const int tile_col = swz & 15;

  const int tid = threadIdx.x;
  const int l = tid & 63;
  const int w = tid >> 6;
  const int wr = w >> 2;      // 0..1 (64-row slice within each 128 region)
  const int wc = w & 3;       // 0..3 (32-col slice within each 128 region)
  const int l31 = l & 31;
  const int kh = l >> 5;      // 16B half of the 32B K-chunk

  // ---- staging pointers: 8 per-thread pre-swizzled sources (bytes) ------
  const char *pA00, *pA01, *pA10, *pA11, *pB00, *pB01, *pB10, *pB11;
  {
    const int ch0 = tid, ch1 = 512 + tid;
    const int r0 = ch0 >> 3, r1 = ch1 >> 3;
    const int c0 = ((ch0 & 7) ^ (r0 & 7) ^ ((r0 >> 3) & 3)) * 16;
    const int c1 = ((ch1 & 7) ^ (r1 & 7) ^ ((r1 >> 3) & 3)) * 16;
    pA00 = A + (size_t)(tile_row * 256 + r0) * N + c0;
    pA01 = A + (size_t)(tile_row * 256 + r1) * N + c1;
    pA10 = A + (size_t)(tile_row * 256 + 128 + r0) * N + c0;
    pA11 = A + (size_t)(tile_row * 256 + 128 + r1) * N + c1;
    pB00 = B + (size_t)(tile_col * 256 + r0) * N + c0;
    pB01 = B + (size_t)(tile_col * 256 + r1) * N + c1;
    pB10 = B + (size_t)(tile_col * 256 + 128 + r0) * N + c0;
    pB11 = B + (size_t)(tile_col * 256 + 128 + r1) * N + c1;
  }

#define GLD(SRC, DST)                                              \
  __builtin_amdgcn_global_load_lds(                                \
      (__attribute__((address_space(1))) void*)(SRC),              \
      (__attribute__((address_space(3))) void*)(DST), 16, 0, 0)
#define STG(REGOFF, P0, P1, KOFF) {                                \
    GLD((P0) + (KOFF), smem + (REGOFF) + w * 1024);                \
    GLD((P1) + (KOFF), smem + (REGOFF) + 8192 + w * 1024); }

  // ---- fragment addressing -----------------------------------------------
  // A-frag (QM region, mf, ks): row = wr*64 + mf*32 + l31 (within region),
  //   K 16B-slot = ks*2 + kh, swizzled ^ fl where fl = (l31&7)^((l31>>3)&3)
  //   (row&7 == l31&7 and (row>>3)&3 == (l31>>3)&3 for all frag rows).
  const int fl = (l31 & 7) ^ ((l31 >> 3) & 3);
  const int rbA = (wr * 64 + l31) * 128;
  const int rbB = 32768 + (wc * 32 + l31) * 128;
  int sxk[4];
#pragma unroll
  for (int ks = 0; ks < 4; ++ks) sxk[ks] = (((ks << 1) + kh) ^ fl) << 4;

  i32x4 aC[2][4], bQ0[4], bQ1[4];
  i32x16 acc[2][2][2];   // [QM][mf][QN]
#pragma unroll
  for (int qm = 0; qm < 2; ++qm)
#pragma unroll
    for (int mf = 0; mf < 2; ++mf)
#pragma unroll
      for (int qn = 0; qn < 2; ++qn)
#pragma unroll
        for (int rg = 0; rg < 16; ++rg) acc[qm][mf][qn][rg] = 0;

#define RD_A(BUFB, QM) { _Pragma("unroll")                                    \
    for (int mf = 0; mf < 2; ++mf)                                            \
    _Pragma("unroll") for (int ks = 0; ks < 4; ++ks)                          \
      aC[mf][ks] = *(const i32x4*)(smem + (BUFB) + (QM)*16384 + rbA +         \
                                   mf*4096 + sxk[ks]); }
#define RD_B(DST, BUFB, QN) { _Pragma("unroll")                               \
    for (int ks = 0; ks < 4; ++ks)                                            \
      DST[ks] = *(const i32x4*)(smem + (BUFB) + (QN)*16384 + rbB + sxk[ks]); }

#define MFQ(QM, QN, BF) {                                                     \
    __builtin_amdgcn_s_setprio(1);                                            \
    _Pragma("unroll") for (int ks = 0; ks < 4; ++ks)                          \
    _Pragma("unroll") for (int mf = 0; mf < 2; ++mf)                          \
      acc[QM][mf][QN] = __builtin_amdgcn_mfma_i32_32x32x32_i8(                \
          aC[mf][ks], BF[ks], acc[QM][mf][QN], 0, 0, 0);                      \
    __builtin_amdgcn_s_setprio(0); }

#define SB   __builtin_amdgcn_sched_barrier(0);
#define BAR  __builtin_amdgcn_s_barrier();
#define VMW2 asm volatile("s_waitcnt vmcnt(2)" ::: "memory");
#define VMW4 asm volatile("s_waitcnt vmcnt(4)" ::: "memory");
#define VMW0 asm volatile("s_waitcnt vmcnt(0)" ::: "memory");
#define LGW4 { asm volatile("s_waitcnt lgkmcnt(4)" ::: "memory"); SB }
#define LGW0 { asm volatile("s_waitcnt lgkmcnt(0)" ::: "memory"); SB }

  // ---- prologue: stage T0 (A0,B0,B1,A1), gate first half, prime q0 ------
  STG(0, pA00, pA01, 0);          // A0(T0)
  STG(32768, pB00, pB01, 0);      // B0(T0)
  STG(49152, pB10, pB11, 0);      // B1(T0)
  STG(16384, pA10, pA11, 0);      // A1(T0)
  VMW4; BAR; SB;
  RD_A(0, 0); RD_B(bQ0, 0, 0);    // q0(T0): 12 reads

  // ---- main loop: iter k computes K-tiles T=2k (buf0), T+1 (buf1) -------
#pragma unroll 1
  for (int k = 0; k < 15; ++k) {
    // ph1: Q00(T); stage A0(T+1)
    VMW2; BAR; SB;
    RD_B(bQ1, 0, 1);
    STG(65536, pA00, pA01, 128);
    LGW4;
    MFQ(0, 0, bQ0);
    // ph2: Q01(T); stage B0(T+1)
    VMW2; BAR;
    STG(98304, pB00, pB01, 128);
    LGW0;
    MFQ(0, 1, bQ1);
    SB;
    RD_A(0, 1);
    // ph3: Q11(T); stage B1(T+1)
    BAR;
    STG(114688, pB10, pB11, 128);
    LGW0;
    MFQ(1, 1, bQ1);
    // ph4: Q10(T); stage A1(T+1)
    VMW2; BAR;
    STG(81920, pA10, pA11, 128);
    MFQ(1, 0, bQ0);
    SB;
    RD_A(65536, 0); RD_B(bQ0, 65536, 0);   // q0(T+1)
    // ph5: Q00(T+1); stage A0(T+2)
    VMW2; BAR; SB;
    RD_B(bQ1, 65536, 1);
    STG(0, pA00, pA01, 256);
    LGW4;
    MFQ(0, 0, bQ0);
    // ph6: Q01(T+1); stage B0(T+2)
    VMW2; BAR;
    STG(32768, pB00, pB01, 256);
    LGW0;
    MFQ(0, 1, bQ1);
    SB;
    RD_A(65536, 1);
    // ph7: Q11(T+1); stage B1(T+2)
    BAR;
    STG(49152, pB10, pB11, 256);
    LGW0;
    MFQ(1, 1, bQ1);
    // ph8: Q10(T+1); stage A1(T+2)
    VMW2; BAR;
    STG(16384, pA10, pA11, 256);
    MFQ(1, 0, bQ0);
    SB;
    RD_A(0, 0); RD_B(bQ0, 0, 0);           // q0(T+2)
    pA00 += 256; pA01 += 256; pA10 += 256; pA11 += 256;
    pB00 += 256; pB01 += 256; pB10 += 256; pB11 += 256;
  }

  // ---- tail: T=30 (buf0), T=31 (buf1); stage T31 in t-ph1..4 ------------
  // t-ph1
  VMW2; BAR; SB;
  RD_B(bQ1, 0, 1);
  STG(65536, pA00, pA01, 128);
  LGW4;
  MFQ(0, 0, bQ0);
  // t-ph2
  VMW2; BAR;
  STG(98304, pB00, pB01, 128);
  LGW0;
  MFQ(0, 1, bQ1);
  SB;
  RD_A(0, 1);
  // t-ph3
  BAR;
  STG(114688, pB10, pB11, 128);
  LGW0;
  MFQ(1, 1, bQ1);
  // t-ph4
  VMW2; BAR;
  STG(81920, pA10, pA11, 128);
  MFQ(1, 0, bQ0);
  SB;
  RD_A(65536, 0); RD_B(bQ0, 65536, 0);
  // t-ph5
  VMW2; BAR; SB;
  RD_B(bQ1, 65536, 1);
  LGW4;
  MFQ(0, 0, bQ0);
  // t-ph6
  VMW0; BAR;
  LGW0;
  MFQ(0, 1, bQ1);
  SB;
  RD_A(65536, 1);
  // t-ph7
  LGW0;
  MFQ(1, 1, bQ1);
  // t-ph8
  MFQ(1, 0, bQ0);

  // ---- epilogue: sim = acc * sx*sy / max(nx*ny, 1e-8) -------------------
  // 32x32 C/D layout (HW-verified, dtype-independent):
  //   col = l&31, row = (reg&3) + 8*(reg>>2) + 4*(l>>5)
  const float* nx = norms;
  const float* ny = norms + N;
  const float* sxp = scales;
  const float* syp = scales + N;
#pragma unroll
  for (int qm = 0; qm < 2; ++qm) {
#pragma unroll
    for (int mf = 0; mf < 2; ++mf) {
#pragma unroll
      for (int rg = 0; rg < 4; ++rg) {       // reg>>2
#pragma unroll
        for (int rr = 0; rr < 4; ++rr) {     // reg&3
          const int row = tile_row * 256 + qm * 128 + wr * 64 + mf * 32 +
                          rg * 8 + rr + 4 * kh;
          const float nxr = nx[row];
          const float sxr = sxp[row];
#pragma unroll
          for (int qn = 0; qn < 2; ++qn) {
            const int col = tile_col * 256 + qn * 128 + wc * 32 + l31;
            const float denom = fmaxf(nxr * ny[col], 1e-8f);
            out[(size_t)row * N + col] =
                (float)acc[qm][mf][qn][rg * 4 + rr] * (sxr * syp[col]) / denom;
          }
        }
      }
    }
  }
}

extern "C" void kernel_launch(void* const* d_in, const int* in_sizes, int n_in,
                              void* d_out, int out_size, void* d_ws, size_t ws_size,
                              hipStream_t stream) {
  const float* Z = (const float*)d_in[0];
  const float* Y = (const float*)d_in[1];
  float* out = (float*)d_out;

  // workspace: Zq (16MB) | Yq (16MB) | norms (32KB) | scales (32KB)
  char* Zq = (char*)d_ws;
  char* Yq = Zq + (size_t)N * N;
  float* norms = (float*)(Yq + (size_t)N * N);
  float* scales = norms + 2 * N;

  prep_kernel<<<2 * N, 256, 0, stream>>>(Z, Y, Zq, Yq, norms, scales);
  gemm_kernel<<<(N / 256) * (N / 256), 512, 0, stream>>>(Zq, Yq, norms, scales,
                                                         out);
}

// Round 16
// 90.335 us; speedup vs baseline: 1.1042x; 1.1042x over previous
//
#include <hip/hip_runtime.h>

typedef __attribute__((ext_vector_type(4))) int i32x4;

#define N 4096

// One block per row (8192 rows: Z then Y). fp32 row norm + absmax + i8 quant.
__global__ __launch_bounds__(256) void prep_kernel(
    const float* __restrict__ Z, const float* __restrict__ Y,
    char* __restrict__ Zq, char* __restrict__ Yq,
    float* __restrict__ norms, float* __restrict__ scales) {
  const int r = blockIdx.x;
  const bool isZ = (r < N);
  const int rr = isZ ? r : r - N;
  const float* __restrict__ src = (isZ ? Z : Y) + (size_t)rr * N;
  char* __restrict__ dst = (isZ ? Zq : Yq) + (size_t)rr * N;
  const int t = threadIdx.x;

  float4 v[4];
  float s = 0.f, amax = 0.f;
#pragma unroll
  for (int j = 0; j < 4; ++j) {
    v[j] = ((const float4*)src)[t * 4 + j];   // lane owns bytes [64t, 64t+64)
    s += v[j].x * v[j].x + v[j].y * v[j].y + v[j].z * v[j].z + v[j].w * v[j].w;
    amax = fmaxf(amax, fmaxf(fmaxf(fabsf(v[j].x), fabsf(v[j].y)),
                             fmaxf(fabsf(v[j].z), fabsf(v[j].w))));
  }
#pragma unroll
  for (int off = 32; off > 0; off >>= 1) {
    s += __shfl_down(s, off, 64);
    amax = fmaxf(amax, __shfl_down(amax, off, 64));
  }
  __shared__ float reds[4], redm[4];
  const int lane = t & 63, w = t >> 6;
  if (lane == 0) { reds[w] = s; redm[w] = amax; }
  __syncthreads();
  const float bmax = fmaxf(fmaxf(redm[0], redm[1]), fmaxf(redm[2], redm[3]));
  if (t == 0) {
    norms[r] = sqrtf(reds[0] + reds[1] + reds[2] + reds[3]);
    scales[r] = bmax * (1.0f / 127.0f);
  }
  const float inv = (bmax > 0.f) ? (127.0f / bmax) : 0.f;
  int q[16];
#pragma unroll
  for (int j = 0; j < 4; ++j) {
    q[4 * j + 0] = __float2int_rn(v[j].x * inv);
    q[4 * j + 1] = __float2int_rn(v[j].y * inv);
    q[4 * j + 2] = __float2int_rn(v[j].z * inv);
    q[4 * j + 3] = __float2int_rn(v[j].w * inv);
  }
  int4 o;
  o.x = (q[0] & 255) | ((q[1] & 255) << 8) | ((q[2] & 255) << 16) | (q[3] << 24);
  o.y = (q[4] & 255) | ((q[5] & 255) << 8) | ((q[6] & 255) << 16) | (q[7] << 24);
  o.z = (q[8] & 255) | ((q[9] & 255) << 8) | ((q[10] & 255) << 16) | (q[11] << 24);
  o.w = (q[12] & 255) | ((q[13] & 255) << 8) | ((q[14] & 255) << 16) | (q[15] << 24);
  ((int4*)dst)[t] = o;
}

// ---- 256x256 tile, K-tile = 128 i8, 8 waves, 2-deep dbuf, 8-phase -------
// Reads pipelined one phase ahead with counted lgkmcnt; vmcnt(2) gates
// (audited minimal: each gate drains exactly the needed regions).
// MFMA: mfma_i32_16x16x64_i8 -- 8 independent acc chains of length 2 per
// phase (vs 2 chains of 4 for 32x32, which measured slower in r15).
// Regions per buf: A0@0 A1@16K B0@32K B1@48K; buf1 = +64K.
// Swizzle: 16B slot ^= (row & 7), both sides (involution).
__global__ __launch_bounds__(512, 2) void gemm_kernel(
    const char* __restrict__ A,       // Zq [N][N] i8
    const char* __restrict__ B,       // Yq [N][N] i8
    const float* __restrict__ norms,  // [2N]: nx then ny
    const float* __restrict__ scales, // [2N]: sx then sy
    float* __restrict__ out) {
  __shared__ __align__(16) char smem[131072];

  const int bid = blockIdx.x;                 // 256 blocks; bijective
  const int swz = (bid & 7) * 32 + (bid >> 3);
  const int tile_row = swz >> 4;
  const int tile_col = swz & 15;

  const int tid = threadIdx.x;
  const int l = tid & 63;
  const int w = tid >> 6;
  const int wr = w >> 2;      // 0..1
  const int wc = w & 3;       // 0..3
  const int li = l & 15;
  const int sl = l >> 4;

  // ---- staging pointers: 8 per-thread pre-swizzled sources (bytes) ------
  const char *pA00, *pA01, *pA10, *pA11, *pB00, *pB01, *pB10, *pB11;
  {
    const int ch0 = tid, ch1 = 512 + tid;
    const int r0 = ch0 >> 3, r1 = ch1 >> 3;
    const int c0 = ((ch0 & 7) ^ (r0 & 7)) * 16;
    const int c1 = ((ch1 & 7) ^ (r1 & 7)) * 16;
    pA00 = A + (size_t)(tile_row * 256 + r0) * N + c0;
    pA01 = A + (size_t)(tile_row * 256 + r1) * N + c1;
    pA10 = A + (size_t)(tile_row * 256 + 128 + r0) * N + c0;
    pA11 = A + (size_t)(tile_row * 256 + 128 + r1) * N + c1;
    pB00 = B + (size_t)(tile_col * 256 + r0) * N + c0;
    pB01 = B + (size_t)(tile_col * 256 + r1) * N + c1;
    pB10 = B + (size_t)(tile_col * 256 + 128 + r0) * N + c0;
    pB11 = B + (size_t)(tile_col * 256 + 128 + r1) * N + c1;
  }

#define GLD(SRC, DST)                                              \
  __builtin_amdgcn_global_load_lds(                                \
      (__attribute__((address_space(1))) void*)(SRC),              \
      (__attribute__((address_space(3))) void*)(DST), 16, 0, 0)
#define STG(REGOFF, P0, P1, KOFF) {                                \
    GLD((P0) + (KOFF), smem + (REGOFF) + w * 1024);                \
    GLD((P1) + (KOFF), smem + (REGOFF) + 8192 + w * 1024); }

  // ---- fragment addressing (bytes) --------------------------------------
  const int rbA = (wr * 64 + li) * 128;
  const int rbB = (wc * 32 + li) * 128;
  const int sx0 = ((sl) ^ (li & 7)) * 16;
  const int sx1 = ((4 + sl) ^ (li & 7)) * 16;

  i32x4 aC[4][2], bQ0[2][2], bQ1[2][2];
  i32x4 acc[8][4];
#pragma unroll
  for (int m = 0; m < 8; ++m)
#pragma unroll
    for (int n = 0; n < 4; ++n) acc[m][n] = (i32x4){0, 0, 0, 0};

#define RD_A(BUFB, QH) { _Pragma("unroll")                                    \
    for (int mfl = 0; mfl < 4; ++mfl) {                                       \
      aC[mfl][0] = *(const i32x4*)(smem + (BUFB) + (QH)*16384 + rbA +         \
                                   mfl*2048 + sx0);                           \
      aC[mfl][1] = *(const i32x4*)(smem + (BUFB) + (QH)*16384 + rbA +         \
                                   mfl*2048 + sx1); } }
#define RD_B(DST, BUFB, QH) { _Pragma("unroll")                               \
    for (int nfl = 0; nfl < 2; ++nfl) {                                       \
      DST[nfl][0] = *(const i32x4*)(smem + (BUFB) + 32768 + (QH)*16384 +      \
                                    rbB + nfl*2048 + sx0);                    \
      DST[nfl][1] = *(const i32x4*)(smem + (BUFB) + 32768 + (QH)*16384 +      \
                                    rbB + nfl*2048 + sx1); } }

#define MFQ(QM, QN, BF) {                                                     \
    __builtin_amdgcn_s_setprio(1);                                            \
    _Pragma("unroll") for (int kh = 0; kh < 2; ++kh)                          \
    _Pragma("unroll") for (int mfl = 0; mfl < 4; ++mfl)                       \
    _Pragma("unroll") for (int nfl = 0; nfl < 2; ++nfl)                       \
      acc[(QM)*4+mfl][(QN)*2+nfl] = __builtin_amdgcn_mfma_i32_16x16x64_i8(    \
          aC[mfl][kh], BF[nfl][kh], acc[(QM)*4+mfl][(QN)*2+nfl], 0, 0, 0);    \
    __builtin_amdgcn_s_setprio(0); }

#define SB   __builtin_amdgcn_sched_barrier(0);
#define BAR  __builtin_amdgcn_s_barrier();
#define VMW2 asm volatile("s_waitcnt vmcnt(2)" ::: "memory");
#define VMW4 asm volatile("s_waitcnt vmcnt(4)" ::: "memory");
#define VMW0 asm volatile("s_waitcnt vmcnt(0)" ::: "memory");
#define LGW4 { asm volatile("s_waitcnt lgkmcnt(4)" ::: "memory"); SB }
#define LGW0 { asm volatile("s_waitcnt lgkmcnt(0)" ::: "memory"); SB }

  // ---- prologue: stage T0 (A0,B0,B1,A1), gate first half, prime q0 ------
  STG(0, pA00, pA01, 0);          // A0(T0)
  STG(32768, pB00, pB01, 0);      // B0(T0)
  STG(49152, pB10, pB11, 0);      // B1(T0)
  STG(16384, pA10, pA11, 0);      // A1(T0)
  VMW4; BAR; SB;
  RD_A(0, 0); RD_B(bQ0, 0, 0);    // q0(T0)

  // ---- main loop: iter k computes K-tiles T=2k (buf0), T+1 (buf1) -------
  // K = 4096 i8 = 32 tiles of 128 -> 15 iters + 2-tile tail.
#pragma unroll 1
  for (int k = 0; k < 15; ++k) {
    // ph1: Q00(T); stage A0(T+1)
    VMW2; BAR; SB;
    RD_B(bQ1, 0, 1);
    STG(65536, pA00, pA01, 128);
    LGW4;
    MFQ(0, 0, bQ0);
    // ph2: Q01(T); stage B0(T+1)
    VMW2; BAR;
    STG(98304, pB00, pB01, 128);
    LGW0;
    MFQ(0, 1, bQ1);
    SB;
    RD_A(0, 1);
    // ph3: Q11(T); stage B1(T+1)
    BAR;
    STG(114688, pB10, pB11, 128);
    LGW0;
    MFQ(1, 1, bQ1);
    // ph4: Q10(T); stage A1(T+1)
    VMW2; BAR;
    STG(81920, pA10, pA11, 128);
    MFQ(1, 0, bQ0);
    SB;
    RD_A(65536, 0); RD_B(bQ0, 65536, 0);   // q0(T+1)
    // ph5: Q00(T+1); stage A0(T+2)
    VMW2; BAR; SB;
    RD_B(bQ1, 65536, 1);
    STG(0, pA00, pA01, 256);
    LGW4;
    MFQ(0, 0, bQ0);
    // ph6: Q01(T+1); stage B0(T+2)
    VMW2; BAR;
    STG(32768, pB00, pB01, 256);
    LGW0;
    MFQ(0, 1, bQ1);
    SB;
    RD_A(65536, 1);
    // ph7: Q11(T+1); stage B1(T+2)
    BAR;
    STG(49152, pB10, pB11, 256);
    LGW0;
    MFQ(1, 1, bQ1);
    // ph8: Q10(T+1); stage A1(T+2)
    VMW2; BAR;
    STG(16384, pA10, pA11, 256);
    MFQ(1, 0, bQ0);
    SB;
    RD_A(0, 0); RD_B(bQ0, 0, 0);           // q0(T+2)
    pA00 += 256; pA01 += 256; pA10 += 256; pA11 += 256;
    pB00 += 256; pB01 += 256; pB10 += 256; pB11 += 256;
  }

  // ---- tail: T=30 (buf0), T=31 (buf1); stage T31 in t-ph1..4 ------------
  // t-ph1
  VMW2; BAR; SB;
  RD_B(bQ1, 0, 1);
  STG(65536, pA00, pA01, 128);
  LGW4;
  MFQ(0, 0, bQ0);
  // t-ph2
  VMW2; BAR;
  STG(98304, pB00, pB01, 128);
  LGW0;
  MFQ(0, 1, bQ1);
  SB;
  RD_A(0, 1);
  // t-ph3
  BAR;
  STG(114688, pB10, pB11, 128);
  LGW0;
  MFQ(1, 1, bQ1);
  // t-ph4
  VMW2; BAR;
  STG(81920, pA10, pA11, 128);
  MFQ(1, 0, bQ0);
  SB;
  RD_A(65536, 0); RD_B(bQ0, 65536, 0);
  // t-ph5
  VMW2; BAR; SB;
  RD_B(bQ1, 65536, 1);
  LGW4;
  MFQ(0, 0, bQ0);
  // t-ph6
  VMW0; BAR;
  LGW0;
  MFQ(0, 1, bQ1);
  SB;
  RD_A(65536, 1);
  // t-ph7
  LGW0;
  MFQ(1, 1, bQ1);
  // t-ph8
  MFQ(1, 0, bQ0);

  // ---- epilogue: sim = acc * sx*sy / max(nx*ny, 1e-8) -------------------
  // C/D layout (16x16, dtype-independent): row=(l>>4)*4+r, col=l&15
  const float* nx = norms;
  const float* ny = norms + N;
  const float* sxp = scales;
  const float* syp = scales + N;
#pragma unroll
  for (int mf = 0; mf < 8; ++mf) {
#pragma unroll
    for (int r = 0; r < 4; ++r) {
      const int row = tile_row * 256 + (mf >> 2) * 128 + wr * 64 +
                      (mf & 3) * 16 + sl * 4 + r;
      const float nxr = nx[row];
      const float sxr = sxp[row];
#pragma unroll
      for (int nf = 0; nf < 4; ++nf) {
        const int col = tile_col * 256 + (nf >> 1) * 128 + wc * 32 +
                        (nf & 1) * 16 + li;
        const float denom = fmaxf(nxr * ny[col], 1e-8f);
        out[(size_t)row * N + col] =
            (float)acc[mf][nf][r] * (sxr * syp[col]) / denom;
      }
    }
  }
}

extern "C" void kernel_launch(void* const* d_in, const int* in_sizes, int n_in,
                              void* d_out, int out_size, void* d_ws, size_t ws_size,
                              hipStream_t stream) {
  const float* Z = (const float*)d_in[0];
  const float* Y = (const float*)d_in[1];
  float* out = (float*)d_out;

  // workspace: Zq (16MB) | Yq (16MB) | norms (32KB) | scales (32KB)
  char* Zq = (char*)d_ws;
  char* Yq = Zq + (size_t)N * N;
  float* norms = (float*)(Yq + (size_t)N * N);
  float* scales = norms + 2 * N;

  prep_kernel<<<2 * N, 256, 0, stream>>>(Z, Y, Zq, Yq, norms, scales);
  gemm_kernel<<<(N / 256) * (N / 256), 512, 0, stream>>>(Zq, Yq, norms, scales,
                                                         out);
}

// Round 17
// 89.482 us; speedup vs baseline: 1.1147x; 1.0095x over previous
//
#include <hip/hip_runtime.h>

typedef __attribute__((ext_vector_type(4))) int i32x4;

#define N 4096

// One block per row (8192 rows: Z then Y). fp32 row norm + absmax + i8 quant.
__global__ __launch_bounds__(256) void prep_kernel(
    const float* __restrict__ Z, const float* __restrict__ Y,
    char* __restrict__ Zq, char* __restrict__ Yq,
    float* __restrict__ norms, float* __restrict__ scales) {
  const int r = blockIdx.x;
  const bool isZ = (r < N);
  const int rr = isZ ? r : r - N;
  const float* __restrict__ src = (isZ ? Z : Y) + (size_t)rr * N;
  char* __restrict__ dst = (isZ ? Zq : Yq) + (size_t)rr * N;
  const int t = threadIdx.x;

  float4 v[4];
  float s = 0.f, amax = 0.f;
#pragma unroll
  for (int j = 0; j < 4; ++j) {
    v[j] = ((const float4*)src)[t * 4 + j];
    s += v[j].x * v[j].x + v[j].y * v[j].y + v[j].z * v[j].z + v[j].w * v[j].w;
    amax = fmaxf(amax, fmaxf(fmaxf(fabsf(v[j].x), fabsf(v[j].y)),
                             fmaxf(fabsf(v[j].z), fabsf(v[j].w))));
  }
#pragma unroll
  for (int off = 32; off > 0; off >>= 1) {
    s += __shfl_down(s, off, 64);
    amax = fmaxf(amax, __shfl_down(amax, off, 64));
  }
  __shared__ float reds[4], redm[4];
  const int lane = t & 63, w = t >> 6;
  if (lane == 0) { reds[w] = s; redm[w] = amax; }
  __syncthreads();
  const float bmax = fmaxf(fmaxf(redm[0], redm[1]), fmaxf(redm[2], redm[3]));
  if (t == 0) {
    norms[r] = sqrtf(reds[0] + reds[1] + reds[2] + reds[3]);
    scales[r] = bmax * (1.0f / 127.0f);
  }
  const float inv = (bmax > 0.f) ? (127.0f / bmax) : 0.f;
  int q[16];
#pragma unroll
  for (int j = 0; j < 4; ++j) {
    q[4 * j + 0] = __float2int_rn(v[j].x * inv);
    q[4 * j + 1] = __float2int_rn(v[j].y * inv);
    q[4 * j + 2] = __float2int_rn(v[j].z * inv);
    q[4 * j + 3] = __float2int_rn(v[j].w * inv);
  }
  int4 o;
  o.x = (q[0] & 255) | ((q[1] & 255) << 8) | ((q[2] & 255) << 16) | (q[3] << 24);
  o.y = (q[4] & 255) | ((q[5] & 255) << 8) | ((q[6] & 255) << 16) | (q[7] << 24);
  o.z = (q[8] & 255) | ((q[9] & 255) << 8) | ((q[10] & 255) << 16) | (q[11] << 24);
  o.w = (q[12] & 255) | ((q[13] & 255) << 8) | ((q[14] & 255) << 16) | (q[15] << 24);
  ((int4*)dst)[t] = o;
}

// ---- 256x256 tile, K-tile = 128 i8, 8 waves, 2-deep dbuf ----------------
// r14 pipeline with sync count HALVED: barriers/gates only at ph2/4/6/8.
// Stage groups: G1={A0,B0,B1}(T+1)@ph1, G2={A1(T+1)}@ph2,
//   G3={A0,B0,B1}(T+2)@ph4-5, G4={A1(T+2)}@ph6.
// Gates (counted, never 0): ph2 VMW6 drains prev-G4; ph4 VMW2 drains G1;
//   ph6 VMW6 drains G2; ph8 VMW2 drains G3. Each stage has >=2-phase slack.
// Reads one phase ahead with counted lgkmcnt (r11/r14 discipline).
// Regions per buf: A0@0 A1@16K B0@32K B1@48K; buf1 = +64K.
// Swizzle: 16B slot ^= (row & 7), both sides (involution).
__global__ __launch_bounds__(512, 2) void gemm_kernel(
    const char* __restrict__ A,       // Zq [N][N] i8
    const char* __restrict__ B,       // Yq [N][N] i8
    const float* __restrict__ norms,  // [2N]: nx then ny
    const float* __restrict__ scales, // [2N]: sx then sy
    float* __restrict__ out) {
  __shared__ __align__(16) char smem[131072];

  const int bid = blockIdx.x;                 // 256 blocks; bijective
  const int swz = (bid & 7) * 32 + (bid >> 3);
  const int tile_row = swz >> 4;
  const int tile_col = swz & 15;

  const int tid = threadIdx.x;
  const int l = tid & 63;
  const int w = tid >> 6;
  const int wr = w >> 2;      // 0..1
  const int wc = w & 3;       // 0..3
  const int li = l & 15;
  const int sl = l >> 4;

  // ---- staging pointers: 8 per-thread pre-swizzled sources (bytes) ------
  const char *pA00, *pA01, *pA10, *pA11, *pB00, *pB01, *pB10, *pB11;
  {
    const int ch0 = tid, ch1 = 512 + tid;
    const int r0 = ch0 >> 3, r1 = ch1 >> 3;
    const int c0 = ((ch0 & 7) ^ (r0 & 7)) * 16;
    const int c1 = ((ch1 & 7) ^ (r1 & 7)) * 16;
    pA00 = A + (size_t)(tile_row * 256 + r0) * N + c0;
    pA01 = A + (size_t)(tile_row * 256 + r1) * N + c1;
    pA10 = A + (size_t)(tile_row * 256 + 128 + r0) * N + c0;
    pA11 = A + (size_t)(tile_row * 256 + 128 + r1) * N + c1;
    pB00 = B + (size_t)(tile_col * 256 + r0) * N + c0;
    pB01 = B + (size_t)(tile_col * 256 + r1) * N + c1;
    pB10 = B + (size_t)(tile_col * 256 + 128 + r0) * N + c0;
    pB11 = B + (size_t)(tile_col * 256 + 128 + r1) * N + c1;
  }

#define GLD(SRC, DST)                                              \
  __builtin_amdgcn_global_load_lds(                                \
      (__attribute__((address_space(1))) void*)(SRC),              \
      (__attribute__((address_space(3))) void*)(DST), 16, 0, 0)
#define STG(REGOFF, P0, P1, KOFF) {                                \
    GLD((P0) + (KOFF), smem + (REGOFF) + w * 1024);                \
    GLD((P1) + (KOFF), smem + (REGOFF) + 8192 + w * 1024); }

  // ---- fragment addressing (bytes) --------------------------------------
  const int rbA = (wr * 64 + li) * 128;
  const int rbB = (wc * 32 + li) * 128;
  const int sx0 = ((sl) ^ (li & 7)) * 16;
  const int sx1 = ((4 + sl) ^ (li & 7)) * 16;

  i32x4 aC[4][2], bQ0[2][2], bQ1[2][2];
  i32x4 acc[8][4];
#pragma unroll
  for (int m = 0; m < 8; ++m)
#pragma unroll
    for (int n = 0; n < 4; ++n) acc[m][n] = (i32x4){0, 0, 0, 0};

#define RD_A(BUFB, QH) { _Pragma("unroll")                                    \
    for (int mfl = 0; mfl < 4; ++mfl) {                                       \
      aC[mfl][0] = *(const i32x4*)(smem + (BUFB) + (QH)*16384 + rbA +         \
                                   mfl*2048 + sx0);                           \
      aC[mfl][1] = *(const i32x4*)(smem + (BUFB) + (QH)*16384 + rbA +         \
                                   mfl*2048 + sx1); } }
#define RD_B(DST, BUFB, QH) { _Pragma("unroll")                               \
    for (int nfl = 0; nfl < 2; ++nfl) {                                       \
      DST[nfl][0] = *(const i32x4*)(smem + (BUFB) + 32768 + (QH)*16384 +      \
                                    rbB + nfl*2048 + sx0);                    \
      DST[nfl][1] = *(const i32x4*)(smem + (BUFB) + 32768 + (QH)*16384 +      \
                                    rbB + nfl*2048 + sx1); } }

#define MFQ(QM, QN, BF) {                                                     \
    __builtin_amdgcn_s_setprio(1);                                            \
    _Pragma("unroll") for (int kh = 0; kh < 2; ++kh)                          \
    _Pragma("unroll") for (int mfl = 0; mfl < 4; ++mfl)                       \
    _Pragma("unroll") for (int nfl = 0; nfl < 2; ++nfl)                       \
      acc[(QM)*4+mfl][(QN)*2+nfl] = __builtin_amdgcn_mfma_i32_16x16x64_i8(    \
          aC[mfl][kh], BF[nfl][kh], acc[(QM)*4+mfl][(QN)*2+nfl], 0, 0, 0);    \
    __builtin_amdgcn_s_setprio(0); }

#define SB   __builtin_amdgcn_sched_barrier(0);
#define BAR  __builtin_amdgcn_s_barrier();
#define VMW6 asm volatile("s_waitcnt vmcnt(6)" ::: "memory");
#define VMW2 asm volatile("s_waitcnt vmcnt(2)" ::: "memory");
#define VMW0 asm volatile("s_waitcnt vmcnt(0)" ::: "memory");
#define LGW4 { asm volatile("s_waitcnt lgkmcnt(4)" ::: "memory"); SB }
#define LGW0 { asm volatile("s_waitcnt lgkmcnt(0)" ::: "memory"); SB }

  // ---- prologue: stage full T0 -> buf0; drain; prime q0(T0) -------------
  STG(0, pA00, pA01, 0);          // A0(T0)
  STG(32768, pB00, pB01, 0);      // B0(T0)
  STG(49152, pB10, pB11, 0);      // B1(T0)
  STG(16384, pA10, pA11, 0);      // A1(T0)
  VMW0; BAR; SB;
  RD_A(0, 0); RD_B(bQ0, 0, 0);    // q0(T0)

  // ---- main loop: iter k computes K-tiles T=2k (buf0), T+1 (buf1) -------
  // K = 4096 i8 = 32 tiles of 128 -> 15 iters + 2-tile tail.
#pragma unroll 1
  for (int k = 0; k < 15; ++k) {
    // ph1 (no sync): Q00(T); stage G1 = {A0,B0,B1}(T+1) -> buf1
    RD_B(bQ1, 0, 1);
    STG(65536, pA00, pA01, 128);
    STG(98304, pB00, pB01, 128);
    STG(114688, pB10, pB11, 128);
    LGW4;
    MFQ(0, 0, bQ0);
    // ph2 [gate VMW6: drains prev-G4]: Q01(T); stage G2 = A1(T+1)
    VMW6; BAR;
    STG(81920, pA10, pA11, 128);
    LGW0;
    MFQ(0, 1, bQ1);
    SB;
    RD_A(0, 1);
    // ph3 (no sync): Q11(T)
    LGW0;
    MFQ(1, 1, bQ1);
    // ph4 [gate VMW2: drains G1]: Q10(T); stage A0,B0(T+2) -> buf0
    VMW2; BAR;
    STG(0, pA00, pA01, 256);
    STG(32768, pB00, pB01, 256);
    MFQ(1, 0, bQ0);
    SB;
    RD_A(65536, 0); RD_B(bQ0, 65536, 0);   // q0(T+1)
    // ph5 (no sync): Q00(T+1); stage B1(T+2)
    RD_B(bQ1, 65536, 1);
    STG(49152, pB10, pB11, 256);
    LGW4;
    MFQ(0, 0, bQ0);
    // ph6 [gate VMW6: drains G2]: Q01(T+1); stage G4 = A1(T+2)
    VMW6; BAR;
    STG(16384, pA10, pA11, 256);
    LGW0;
    MFQ(0, 1, bQ1);
    SB;
    RD_A(65536, 1);
    // ph7 (no sync): Q11(T+1)
    LGW0;
    MFQ(1, 1, bQ1);
    // ph8 [gate VMW2: drains G3]: Q10(T+1)
    VMW2; BAR;
    MFQ(1, 0, bQ0);
    SB;
    RD_A(0, 0); RD_B(bQ0, 0, 0);           // q0(T+2)
    pA00 += 256; pA01 += 256; pA10 += 256; pA11 += 256;
    pB00 += 256; pB01 += 256; pB10 += 256; pB11 += 256;
  }

  // ---- tail: T=30 (buf0), T=31 (buf1); stage T31; peel gates ------------
  // t-ph1
  RD_B(bQ1, 0, 1);
  STG(65536, pA00, pA01, 128);
  STG(98304, pB00, pB01, 128);
  STG(114688, pB10, pB11, 128);
  LGW4;
  MFQ(0, 0, bQ0);
  // t-ph2 [VMW6 drains G4 = A1(30)]
  VMW6; BAR;
  STG(81920, pA10, pA11, 128);   // A1(31)
  LGW0;
  MFQ(0, 1, bQ1);
  SB;
  RD_A(0, 1);
  // t-ph3
  LGW0;
  MFQ(1, 1, bQ1);
  // t-ph4 [VMW2 drains {A0,B0,B1}(31)]
  VMW2; BAR;
  MFQ(1, 0, bQ0);
  SB;
  RD_A(65536, 0); RD_B(bQ0, 65536, 0);
  // t-ph5
  RD_B(bQ1, 65536, 1);
  LGW4;
  MFQ(0, 0, bQ0);
  // t-ph6 [VMW0 drains A1(31)]
  VMW0; BAR;
  LGW0;
  MFQ(0, 1, bQ1);
  SB;
  RD_A(65536, 1);
  // t-ph7
  LGW0;
  MFQ(1, 1, bQ1);
  // t-ph8
  MFQ(1, 0, bQ0);

  // ---- epilogue: sim = acc * sx*sy / max(nx*ny, 1e-8) -------------------
  // C/D layout (16x16, dtype-independent): row=(l>>4)*4+r, col=l&15
  const float* nx = norms;
  const float* ny = norms + N;
  const float* sxp = scales;
  const float* syp = scales + N;
#pragma unroll
  for (int mf = 0; mf < 8; ++mf) {
#pragma unroll
    for (int r = 0; r < 4; ++r) {
      const int row = tile_row * 256 + (mf >> 2) * 128 + wr * 64 +
                      (mf & 3) * 16 + sl * 4 + r;
      const float nxr = nx[row];
      const float sxr = sxp[row];
#pragma unroll
      for (int nf = 0; nf < 4; ++nf) {
        const int col = tile_col * 256 + (nf >> 1) * 128 + wc * 32 +
                        (nf & 1) * 16 + li;
        const float denom = fmaxf(nxr * ny[col], 1e-8f);
        out[(size_t)row * N + col] =
            (float)acc[mf][nf][r] * (sxr * syp[col]) / denom;
      }
    }
  }
}

extern "C" void kernel_launch(void* const* d_in, const int* in_sizes, int n_in,
                              void* d_out, int out_size, void* d_ws, size_t ws_size,
                              hipStream_t stream) {
  const float* Z = (const float*)d_in[0];
  const float* Y = (const float*)d_in[1];
  float* out = (float*)d_out;

  // workspace: Zq (16MB) | Yq (16MB) | norms (32KB) | scales (32KB)
  char* Zq = (char*)d_ws;
  char* Yq = Zq + (size_t)N * N;
  float* norms = (float*)(Yq + (size_t)N * N);
  float* scales = norms + 2 * N;

  prep_kernel<<<2 * N, 256, 0, stream>>>(Z, Y, Zq, Yq, norms, scales);
  gemm_kernel<<<(N / 256) * (N / 256), 512, 0, stream>>>(Zq, Yq, norms, scales,
                                                         out);
}

// Round 18
// 88.083 us; speedup vs baseline: 1.1324x; 1.0159x over previous
//
#include <hip/hip_runtime.h>

typedef __attribute__((ext_vector_type(4))) int i32x4;

#define N 4096

// One block per row (8192 rows: Z then Y). Computes rs[r] = (absmax/127)/norm
// (the complete per-row output factor) + i8 quantized row.
__global__ __launch_bounds__(256) void prep_kernel(
    const float* __restrict__ Z, const float* __restrict__ Y,
    char* __restrict__ Zq, char* __restrict__ Yq,
    float* __restrict__ rs) {
  const int r = blockIdx.x;
  const bool isZ = (r < N);
  const int rr = isZ ? r : r - N;
  const float* __restrict__ src = (isZ ? Z : Y) + (size_t)rr * N;
  char* __restrict__ dst = (isZ ? Zq : Yq) + (size_t)rr * N;
  const int t = threadIdx.x;

  float4 v[4];
  float s = 0.f, amax = 0.f;
#pragma unroll
  for (int j = 0; j < 4; ++j) {
    v[j] = ((const float4*)src)[t * 4 + j];
    s += v[j].x * v[j].x + v[j].y * v[j].y + v[j].z * v[j].z + v[j].w * v[j].w;
    amax = fmaxf(amax, fmaxf(fmaxf(fabsf(v[j].x), fabsf(v[j].y)),
                             fmaxf(fabsf(v[j].z), fabsf(v[j].w))));
  }
#pragma unroll
  for (int off = 32; off > 0; off >>= 1) {
    s += __shfl_down(s, off, 64);
    amax = fmaxf(amax, __shfl_down(amax, off, 64));
  }
  __shared__ float reds[4], redm[4];
  const int lane = t & 63, w = t >> 6;
  if (lane == 0) { reds[w] = s; redm[w] = amax; }
  __syncthreads();
  const float bmax = fmaxf(fmaxf(redm[0], redm[1]), fmaxf(redm[2], redm[3]));
  if (t == 0) {
    const float nrm = sqrtf(reds[0] + reds[1] + reds[2] + reds[3]);
    // complete per-row factor: scale / norm (clamp unreachable for N(0,1))
    rs[r] = (bmax * (1.0f / 127.0f)) / fmaxf(nrm, 1e-20f);
  }
  const float inv = (bmax > 0.f) ? (127.0f / bmax) : 0.f;
  int q[16];
#pragma unroll
  for (int j = 0; j < 4; ++j) {
    q[4 * j + 0] = __float2int_rn(v[j].x * inv);
    q[4 * j + 1] = __float2int_rn(v[j].y * inv);
    q[4 * j + 2] = __float2int_rn(v[j].z * inv);
    q[4 * j + 3] = __float2int_rn(v[j].w * inv);
  }
  int4 o;
  o.x = (q[0] & 255) | ((q[1] & 255) << 8) | ((q[2] & 255) << 16) | (q[3] << 24);
  o.y = (q[4] & 255) | ((q[5] & 255) << 8) | ((q[6] & 255) << 16) | (q[7] << 24);
  o.z = (q[8] & 255) | ((q[9] & 255) << 8) | ((q[10] & 255) << 16) | (q[11] << 24);
  o.w = (q[12] & 255) | ((q[13] & 255) << 8) | ((q[14] & 255) << 16) | (q[15] << 24);
  ((int4*)dst)[t] = o;
}

// ---- 256x256 tile, K-tile = 128 i8, 8 waves, 2-deep dbuf ----------------
// r17 schedule (4 sync points/iter, counted vmcnt/lgkm, reads one phase
// ahead). Epilogue: out = acc * rsx[row] * rsy[col] (div/fmax folded into
// prep's reciprocal factor). Regions/buf: A0@0 A1@16K B0@32K B1@48K; +64K.
// Swizzle: 16B slot ^= (row & 7), both sides (involution).
__global__ __launch_bounds__(512, 2) void gemm_kernel(
    const char* __restrict__ A,       // Zq [N][N] i8
    const char* __restrict__ B,       // Yq [N][N] i8
    const float* __restrict__ rs,     // [2N]: rsx then rsy
    float* __restrict__ out) {
  __shared__ __align__(16) char smem[131072];

  const int bid = blockIdx.x;                 // 256 blocks; bijective
  const int swz = (bid & 7) * 32 + (bid >> 3);
  const int tile_row = swz >> 4;
  const int tile_col = swz & 15;

  const int tid = threadIdx.x;
  const int l = tid & 63;
  const int w = tid >> 6;
  const int wr = w >> 2;      // 0..1
  const int wc = w & 3;       // 0..3
  const int li = l & 15;
  const int sl = l >> 4;

  // ---- staging pointers: 8 per-thread pre-swizzled sources (bytes) ------
  const char *pA00, *pA01, *pA10, *pA11, *pB00, *pB01, *pB10, *pB11;
  {
    const int ch0 = tid, ch1 = 512 + tid;
    const int r0 = ch0 >> 3, r1 = ch1 >> 3;
    const int c0 = ((ch0 & 7) ^ (r0 & 7)) * 16;
    const int c1 = ((ch1 & 7) ^ (r1 & 7)) * 16;
    pA00 = A + (size_t)(tile_row * 256 + r0) * N + c0;
    pA01 = A + (size_t)(tile_row * 256 + r1) * N + c1;
    pA10 = A + (size_t)(tile_row * 256 + 128 + r0) * N + c0;
    pA11 = A + (size_t)(tile_row * 256 + 128 + r1) * N + c1;
    pB00 = B + (size_t)(tile_col * 256 + r0) * N + c0;
    pB01 = B + (size_t)(tile_col * 256 + r1) * N + c1;
    pB10 = B + (size_t)(tile_col * 256 + 128 + r0) * N + c0;
    pB11 = B + (size_t)(tile_col * 256 + 128 + r1) * N + c1;
  }

#define GLD(SRC, DST)                                              \
  __builtin_amdgcn_global_load_lds(                                \
      (__attribute__((address_space(1))) void*)(SRC),              \
      (__attribute__((address_space(3))) void*)(DST), 16, 0, 0)
#define STG(REGOFF, P0, P1, KOFF) {                                \
    GLD((P0) + (KOFF), smem + (REGOFF) + w * 1024);                \
    GLD((P1) + (KOFF), smem + (REGOFF) + 8192 + w * 1024); }

  // ---- fragment addressing (bytes) --------------------------------------
  const int rbA = (wr * 64 + li) * 128;
  const int rbB = (wc * 32 + li) * 128;
  const int sx0 = ((sl) ^ (li & 7)) * 16;
  const int sx1 = ((4 + sl) ^ (li & 7)) * 16;

  i32x4 aC[4][2], bQ0[2][2], bQ1[2][2];
  i32x4 acc[8][4];
#pragma unroll
  for (int m = 0; m < 8; ++m)
#pragma unroll
    for (int n = 0; n < 4; ++n) acc[m][n] = (i32x4){0, 0, 0, 0};

#define RD_A(BUFB, QH) { _Pragma("unroll")                                    \
    for (int mfl = 0; mfl < 4; ++mfl) {                                       \
      aC[mfl][0] = *(const i32x4*)(smem + (BUFB) + (QH)*16384 + rbA +         \
                                   mfl*2048 + sx0);                           \
      aC[mfl][1] = *(const i32x4*)(smem + (BUFB) + (QH)*16384 + rbA +         \
                                   mfl*2048 + sx1); } }
#define RD_B(DST, BUFB, QH) { _Pragma("unroll")                               \
    for (int nfl = 0; nfl < 2; ++nfl) {                                       \
      DST[nfl][0] = *(const i32x4*)(smem + (BUFB) + 32768 + (QH)*16384 +      \
                                    rbB + nfl*2048 + sx0);                    \
      DST[nfl][1] = *(const i32x4*)(smem + (BUFB) + 32768 + (QH)*16384 +      \
                                    rbB + nfl*2048 + sx1); } }

#define MFQ(QM, QN, BF) {                                                     \
    __builtin_amdgcn_s_setprio(1);                                            \
    _Pragma("unroll") for (int kh = 0; kh < 2; ++kh)                          \
    _Pragma("unroll") for (int mfl = 0; mfl < 4; ++mfl)                       \
    _Pragma("unroll") for (int nfl = 0; nfl < 2; ++nfl)                       \
      acc[(QM)*4+mfl][(QN)*2+nfl] = __builtin_amdgcn_mfma_i32_16x16x64_i8(    \
          aC[mfl][kh], BF[nfl][kh], acc[(QM)*4+mfl][(QN)*2+nfl], 0, 0, 0);    \
    __builtin_amdgcn_s_setprio(0); }

#define SB   __builtin_amdgcn_sched_barrier(0);
#define BAR  __builtin_amdgcn_s_barrier();
#define VMW6 asm volatile("s_waitcnt vmcnt(6)" ::: "memory");
#define VMW2 asm volatile("s_waitcnt vmcnt(2)" ::: "memory");
#define VMW0 asm volatile("s_waitcnt vmcnt(0)" ::: "memory");
#define LGW4 { asm volatile("s_waitcnt lgkmcnt(4)" ::: "memory"); SB }
#define LGW0 { asm volatile("s_waitcnt lgkmcnt(0)" ::: "memory"); SB }

  // ---- prologue: stage full T0 -> buf0; drain; prime q0(T0) -------------
  STG(0, pA00, pA01, 0);          // A0(T0)
  STG(32768, pB00, pB01, 0);      // B0(T0)
  STG(49152, pB10, pB11, 0);      // B1(T0)
  STG(16384, pA10, pA11, 0);      // A1(T0)
  VMW0; BAR; SB;
  RD_A(0, 0); RD_B(bQ0, 0, 0);    // q0(T0)

  // ---- main loop: iter k computes K-tiles T=2k (buf0), T+1 (buf1) -------
#pragma unroll 1
  for (int k = 0; k < 15; ++k) {
    // ph1 (no sync): Q00(T); stage G1 = {A0,B0,B1}(T+1) -> buf1
    RD_B(bQ1, 0, 1);
    STG(65536, pA00, pA01, 128);
    STG(98304, pB00, pB01, 128);
    STG(114688, pB10, pB11, 128);
    LGW4;
    MFQ(0, 0, bQ0);
    // ph2 [gate VMW6: drains prev-G4]: Q01(T); stage G2 = A1(T+1)
    VMW6; BAR;
    STG(81920, pA10, pA11, 128);
    LGW0;
    MFQ(0, 1, bQ1);
    SB;
    RD_A(0, 1);
    // ph3 (no sync): Q11(T)
    LGW0;
    MFQ(1, 1, bQ1);
    // ph4 [gate VMW2: drains G1]: Q10(T); stage A0,B0(T+2) -> buf0
    VMW2; BAR;
    STG(0, pA00, pA01, 256);
    STG(32768, pB00, pB01, 256);
    MFQ(1, 0, bQ0);
    SB;
    RD_A(65536, 0); RD_B(bQ0, 65536, 0);   // q0(T+1)
    // ph5 (no sync): Q00(T+1); stage B1(T+2)
    RD_B(bQ1, 65536, 1);
    STG(49152, pB10, pB11, 256);
    LGW4;
    MFQ(0, 0, bQ0);
    // ph6 [gate VMW6: drains G2]: Q01(T+1); stage G4 = A1(T+2)
    VMW6; BAR;
    STG(16384, pA10, pA11, 256);
    LGW0;
    MFQ(0, 1, bQ1);
    SB;
    RD_A(65536, 1);
    // ph7 (no sync): Q11(T+1)
    LGW0;
    MFQ(1, 1, bQ1);
    // ph8 [gate VMW2: drains G3]: Q10(T+1)
    VMW2; BAR;
    MFQ(1, 0, bQ0);
    SB;
    RD_A(0, 0); RD_B(bQ0, 0, 0);           // q0(T+2)
    pA00 += 256; pA01 += 256; pA10 += 256; pA11 += 256;
    pB00 += 256; pB01 += 256; pB10 += 256; pB11 += 256;
  }

  // ---- tail: T=30 (buf0), T=31 (buf1); stage T31; peel gates ------------
  // t-ph1
  RD_B(bQ1, 0, 1);
  STG(65536, pA00, pA01, 128);
  STG(98304, pB00, pB01, 128);
  STG(114688, pB10, pB11, 128);
  LGW4;
  MFQ(0, 0, bQ0);
  // t-ph2 [VMW6 drains G4 = A1(30)]
  VMW6; BAR;
  STG(81920, pA10, pA11, 128);   // A1(31)
  LGW0;
  MFQ(0, 1, bQ1);
  SB;
  RD_A(0, 1);
  // t-ph3
  LGW0;
  MFQ(1, 1, bQ1);
  // t-ph4 [VMW2 drains {A0,B0,B1}(31)]
  VMW2; BAR;
  MFQ(1, 0, bQ0);
  SB;
  RD_A(65536, 0); RD_B(bQ0, 65536, 0);
  // t-ph5
  RD_B(bQ1, 65536, 1);
  LGW4;
  MFQ(0, 0, bQ0);
  // t-ph6 [VMW0 drains A1(31)]
  VMW0; BAR;
  LGW0;
  MFQ(0, 1, bQ1);
  SB;
  RD_A(65536, 1);
  // t-ph7
  LGW0;
  MFQ(1, 1, bQ1);
  // t-ph8
  MFQ(1, 0, bQ0);

  // ---- epilogue: sim = acc * rsx[row] * rsy[col] (no div, no clamp) -----
  // C/D layout (16x16, dtype-independent): row=(l>>4)*4+r, col=l&15
  const float* rsx = rs;
  const float* rsy = rs + N;
#pragma unroll
  for (int mf = 0; mf < 8; ++mf) {
#pragma unroll
    for (int r = 0; r < 4; ++r) {
      const int row = tile_row * 256 + (mf >> 2) * 128 + wr * 64 +
                      (mf & 3) * 16 + sl * 4 + r;
      const float fx = rsx[row];
#pragma unroll
      for (int nf = 0; nf < 4; ++nf) {
        const int col = tile_col * 256 + (nf >> 1) * 128 + wc * 32 +
                        (nf & 1) * 16 + li;
        out[(size_t)row * N + col] =
            (float)acc[mf][nf][r] * fx * rsy[col];
      }
    }
  }
}

extern "C" void kernel_launch(void* const* d_in, const int* in_sizes, int n_in,
                              void* d_out, int out_size, void* d_ws, size_t ws_size,
                              hipStream_t stream) {
  const float* Z = (const float*)d_in[0];
  const float* Y = (const float*)d_in[1];
  float* out = (float*)d_out;

  // workspace: Zq (16MB) | Yq (16MB) | rs (32KB)
  char* Zq = (char*)d_ws;
  char* Yq = Zq + (size_t)N * N;
  float* rs = (float*)(Yq + (size_t)N * N);

  prep_kernel<<<2 * N, 256, 0, stream>>>(Z, Y, Zq, Yq, rs);
  gemm_kernel<<<(N / 256) * (N / 256), 512, 0, stream>>>(Zq, Yq, rs, out);
}